// Round 6
// baseline (371.351 us; speedup 1.0000x reference)
//
#include <hip/hip_runtime.h>
#include <math.h>
#include <stdint.h>
#include <stddef.h>

// ---------------------------------------------------------------------------
// SelfAttention forward, fp32 I/O, bf16 MFMA internally.
// Round 6: attention occupancy fix — 128-thread blocks (2 waves x 64 q),
// grid 1024 = 4 blocks/CU (was 512 = 2/CU, the real cap). Q pre-scale now
// log2(e)/8 so softmax is a single v_exp_f32 (exp2) per logit.
// ---------------------------------------------------------------------------

#define SEQ    2048
#define NB     4
#define E_DIM  1024
#define N1     3072
#define M_TOK  8192
#define NHEAD  16
#define DHEAD  64

typedef __attribute__((ext_vector_type(4))) float    floatx4;
typedef __attribute__((ext_vector_type(8))) short    shortx8;
typedef __attribute__((ext_vector_type(4))) unsigned short ushortx4;

#if __has_builtin(__builtin_amdgcn_exp2f)
#define EXP2(x) __builtin_amdgcn_exp2f(x)
#else
#define EXP2(x) __expf((x) * 0.6931471805599453f)
#endif

__device__ __forceinline__ unsigned short f2bf(float f) {
    union { float f; unsigned u; } v; v.f = f;
    unsigned r = (v.u + 0x7FFFu + ((v.u >> 16) & 1u)) >> 16;  // RNE
    return (unsigned short)r;
}
__device__ __forceinline__ unsigned fbits(float f) {
    union { float f; unsigned u; } v; v.f = f; return v.u;
}
__device__ __forceinline__ float bitsf(unsigned u) {
    union { unsigned u; float f; } v; v.u = u; return v.f;
}

__device__ __forceinline__ void gl_lds16(const void* g, void* l) {
    __builtin_amdgcn_global_load_lds(
        (const __attribute__((address_space(1))) unsigned int*)g,
        (__attribute__((address_space(3))) unsigned int*)l, 16, 0, 0);
}

// --------------------------- fp32 -> bf16 convert ---------------------------
__global__ __launch_bounds__(256) void cvt_bf16(
    const float* __restrict__ in, unsigned short* __restrict__ out)
{
    const size_t i = ((size_t)blockIdx.x * 256 + threadIdx.x) * 8;
    float4 a = *(const float4*)(in + i);
    float4 b = *(const float4*)(in + i + 4);
    ushortx4 o0 = { f2bf(a.x), f2bf(a.y), f2bf(a.z), f2bf(a.w) };
    ushortx4 o1 = { f2bf(b.x), f2bf(b.y), f2bf(b.z), f2bf(b.w) };
    *(ushortx4*)(out + i)     = o0;
    *(ushortx4*)(out + i + 4) = o1;
}

// -------------------- fp32 [K][N] -> bf16 transposed [N][K] -----------------
__global__ __launch_bounds__(256) void cvt_transpose(
    const float* __restrict__ W, unsigned short* __restrict__ Wt, int K, int N)
{
    __shared__ unsigned short tile[32][33];
    const int tx = threadIdx.x, ty = threadIdx.y;   // (32, 8)
    const int n0 = blockIdx.x * 32, k0 = blockIdx.y * 32;
#pragma unroll
    for (int r = 0; r < 4; ++r) {
        const int k = ty + r * 8;
        tile[tx][k] = f2bf(W[(size_t)(k0 + k) * N + n0 + tx]);
    }
    __syncthreads();
#pragma unroll
    for (int r = 0; r < 4; ++r) {
        const int n = ty + r * 8;
        Wt[(size_t)(n0 + n) * K + k0 + tx] = tile[n][tx];
    }
}

// --------------------------- bf16 MFMA GEMM --------------------------------
// C[M,N] = A[M,K](bf16) @ Bt[N,K](bf16, pre-transposed) + bias[N](f32).
// FUSE (gemm1 only): Q columns (col%192 < 64) pre-scaled by log2(e)/8 before
// bf16 store (softmax becomes plain exp2); V columns (col%192 >= 128) also
// written transposed into Vt[bh][d][s] (4 consecutive rows per lane -> packed).
template <bool OUT_BF16, bool FUSE>
__global__ __launch_bounds__(256) void gemm_bf16(
    const short* __restrict__ A, const short* __restrict__ Bt,
    const float* __restrict__ bias, void* __restrict__ Cout,
    unsigned short* __restrict__ Vt,
    int M, int N, int K)
{
    __shared__ short As[128 * 32];
    __shared__ short Bs[128 * 32];

    const int t    = threadIdx.x;
    const int lane = t & 63, w = t >> 6;
    const int quad = lane >> 4, l15 = lane & 15;
    const int bm = blockIdx.y * 128, bn = blockIdx.x * 128;
    const int m0w = (w >> 1) * 64, n0w = (w & 1) * 64;

    const int lrow = lane >> 2;        // 0..15
    const int lcol = (lane & 3) * 8;   // 0,8,16,24
    const short* Ag0 = A  + (size_t)(bm + (2 * w + 0) * 16 + lrow) * K + lcol;
    const short* Ag1 = A  + (size_t)(bm + (2 * w + 1) * 16 + lrow) * K + lcol;
    const short* Bg0 = Bt + (size_t)(bn + (2 * w + 0) * 16 + lrow) * K + lcol;
    const short* Bg1 = Bt + (size_t)(bn + (2 * w + 1) * 16 + lrow) * K + lcol;
    short* Al0 = As + (2 * w + 0) * 512;
    short* Al1 = As + (2 * w + 1) * 512;
    short* Bl0 = Bs + (2 * w + 0) * 512;
    short* Bl1 = Bs + (2 * w + 1) * 512;

    floatx4 acc[4][4];
#pragma unroll
    for (int i = 0; i < 4; ++i)
#pragma unroll
        for (int j = 0; j < 4; ++j) acc[i][j] = (floatx4)0.f;

    for (int k0 = 0; k0 < K; k0 += 32) {
        __syncthreads();
        gl_lds16(Ag0, Al0); gl_lds16(Ag1, Al1);
        gl_lds16(Bg0, Bl0); gl_lds16(Bg1, Bl1);
        Ag0 += 32; Ag1 += 32; Bg0 += 32; Bg1 += 32;
        __syncthreads();

        shortx8 af[4], bf[4];
#pragma unroll
        for (int mi = 0; mi < 4; ++mi)
            af[mi] = *(const shortx8*)(As + (m0w + mi * 16 + l15) * 32 + quad * 8);
#pragma unroll
        for (int ni = 0; ni < 4; ++ni)
            bf[ni] = *(const shortx8*)(Bs + (n0w + ni * 16 + l15) * 32 + quad * 8);
#pragma unroll
        for (int mi = 0; mi < 4; ++mi)
#pragma unroll
            for (int ni = 0; ni < 4; ++ni)
                acc[mi][ni] = __builtin_amdgcn_mfma_f32_16x16x32_bf16(
                    af[mi], bf[ni], acc[mi][ni], 0, 0, 0);
    }

    float bv[4];
#pragma unroll
    for (int ni = 0; ni < 4; ++ni) bv[ni] = bias[bn + n0w + ni * 16 + l15];

#pragma unroll
    for (int ni = 0; ni < 4; ++ni) {
        const int col   = bn + n0w + ni * 16 + l15;
        const int cm    = col % 192;      // wave-uniform block (no divergence)
        const int vhead = col / 192;
#pragma unroll
        for (int mi = 0; mi < 4; ++mi) {
            const int row0 = bm + m0w + mi * 16 + quad * 4;
            float v[4];
#pragma unroll
            for (int r = 0; r < 4; ++r) v[r] = acc[mi][ni][r] + bv[ni];
            if (OUT_BF16) {
                if (FUSE && cm < DHEAD) {
#pragma unroll
                    for (int r = 0; r < 4; ++r) v[r] *= 0.18033688011112042f;  // log2(e)/8
                }
                unsigned short* H = (unsigned short*)Cout;
#pragma unroll
                for (int r = 0; r < 4; ++r)
                    H[(size_t)(row0 + r) * N + col] = f2bf(v[r]);
                if (FUSE && cm >= 2 * DHEAD) {
                    const int nb = row0 >> 11;       // batch
                    const int s  = row0 & 2047;
                    const int d  = cm - 2 * DHEAD;
                    ushortx4 pk = { f2bf(v[0]), f2bf(v[1]), f2bf(v[2]), f2bf(v[3]) };
                    *(ushortx4*)(Vt + ((size_t)(nb * NHEAD + vhead) * DHEAD + d) * SEQ + s) = pk;
                }
            } else {
                float* C = (float*)Cout;
#pragma unroll
                for (int r = 0; r < 4; ++r)
                    C[(size_t)(row0 + r) * N + col] = v[r];
            }
        }
    }
}

// ------------------------- MFMA flash attention v6 --------------------------
// Block: 128 threads = 2 waves x 64 q. Grid (64 bh, 16 q-chunks) = 1024 blocks
// = 4 blocks/CU. KV tile 64, S^T = K·Q^T, Q pre-scaled by log2(e)/8 -> exp2.
// XOR-swizzled stride-64 LDS. ~32.5 KB LDS/block.
__global__ __launch_bounds__(128, 2) void attn_mfma(
    const short* __restrict__ h, const short* __restrict__ Vt,
    unsigned short* __restrict__ att)
{
    __shared__ short Ks[64 * 64];      // [kv][d], swizzled
    __shared__ short Vs[64 * 64];      // [d][kv], swizzled
    __shared__ short Pl[2][64 * 64];   // per-wave P [q][kv], swizzled
    __shared__ float Ls[2][64];        // per-wave row sums

    const int t    = threadIdx.x;      // 0..127
    const int lane = t & 63, w = t >> 6;
    const int quad = lane >> 4, l15 = lane & 15;
    const int r7   = l15 & 7;          // read-side swizzle key
    const int bh = blockIdx.x, n = bh >> 4, head = bh & 15;
    const int q0 = blockIdx.y * 128 + w * 64;

    const short* hQ  = h + (size_t)n * SEQ * N1 + head * (3 * DHEAD);
    const short* hK  = hQ + DHEAD;
    const short* Vtb = Vt + (size_t)bh * DHEAD * SEQ;

    // staging: thread t owns row t>>1 (kv for K, d for V), chunks sc0..sc0+3
    const int srow = t >> 1;                    // 0..63
    const int sc0  = (t & 1) * 4;               // chunk base 0 or 4
    const int sk   = srow & 7;                  // write-side swizzle key
    const short* gK = hK  + (size_t)srow * N1  + sc0 * 8;
    const short* gV = Vtb + (size_t)srow * SEQ + sc0 * 8;
    short* lKr = Ks + srow * 64;
    short* lVr = Vs + srow * 64;

    // Q fragments (A-layout register image; serves as B operand for K·Q^T)
    shortx8 qf[4][2];
#pragma unroll
    for (int qt = 0; qt < 4; ++qt)
#pragma unroll
        for (int kt = 0; kt < 2; ++kt)
            qf[qt][kt] = *(const shortx8*)(hQ + (size_t)(q0 + qt * 16 + l15) * N1
                                           + kt * 32 + quad * 8);

    floatx4 O[4][4];
    float lsum[4];
#pragma unroll
    for (int mi = 0; mi < 4; ++mi) {
        lsum[mi] = 0.f;
#pragma unroll
        for (int nt = 0; nt < 4; ++nt) O[mi][nt] = (floatx4)0.f;
    }

    // prefetch tile 0 (4 int4 each for K and V = 32 shorts per thread each)
    int4 kr[4], vr[4];
#pragma unroll
    for (int i = 0; i < 4; ++i) {
        kr[i] = *(const int4*)(gK + i * 8);
        vr[i] = *(const int4*)(gV + i * 8);
    }

    short* Pw = Pl[w];

    for (int kv0 = 0; kv0 < SEQ; kv0 += 64) {
        __syncthreads();
#pragma unroll
        for (int i = 0; i < 4; ++i) {
            *(int4*)(lKr + ((sc0 + i) ^ sk) * 8) = kr[i];
            *(int4*)(lVr + ((sc0 + i) ^ sk) * 8) = vr[i];
        }
        __syncthreads();
        if (kv0 + 64 < SEQ) {
            const short* gKn = gK + (size_t)(kv0 + 64) * N1;
            const short* gVn = gV + (kv0 + 64);
#pragma unroll
            for (int i = 0; i < 4; ++i) {
                kr[i] = *(const int4*)(gKn + i * 8);
                vr[i] = *(const int4*)(gVn + i * 8);
            }
        }

        // S^T tiles: per 16-kv slab, 8 MFMA, then exp2+pack+write
#pragma unroll
        for (int kvt = 0; kvt < 4; ++kvt) {
            const short* krow = Ks + (kvt * 16 + l15) * 64;
            shortx8 kf0 = *(const shortx8*)(krow + ((quad ^ r7) * 8));
            shortx8 kf1 = *(const shortx8*)(krow + (((quad ^ r7) ^ 4) * 8));
            floatx4 s[4];
#pragma unroll
            for (int qt = 0; qt < 4; ++qt) {
                s[qt] = __builtin_amdgcn_mfma_f32_16x16x32_bf16(
                    kf0, qf[qt][0], (floatx4)0.f, 0, 0, 0);
                s[qt] = __builtin_amdgcn_mfma_f32_16x16x32_bf16(
                    kf1, qf[qt][1], s[qt], 0, 0, 0);
            }
#pragma unroll
            for (int qt = 0; qt < 4; ++qt) {
                const float p0 = EXP2(s[qt][0]);
                const float p1 = EXP2(s[qt][1]);
                const float p2 = EXP2(s[qt][2]);
                const float p3 = EXP2(s[qt][3]);
                // truncate-pack pairs (exp>0, trunc ok; lsum uses stored vals)
                const unsigned d01 = __builtin_amdgcn_perm(fbits(p1), fbits(p0), 0x07060302u);
                const unsigned d23 = __builtin_amdgcn_perm(fbits(p3), fbits(p2), 0x07060302u);
                lsum[qt] += bitsf(d01 << 16) + bitsf(d01 & 0xFFFF0000u)
                          + bitsf(d23 << 16) + bitsf(d23 & 0xFFFF0000u);
                uint2 pk = { d01, d23 };
                *(uint2*)(Pw + (qt * 16 + l15) * 64
                          + ((2 * kvt + (quad >> 1)) ^ r7) * 8 + (quad & 1) * 4) = pk;
            }
        }

        // O += P @ V
#pragma unroll
        for (int kt2 = 0; kt2 < 2; ++kt2) {
            const int coff = (((kt2 * 4 + quad) ^ r7)) * 8;
            shortx8 pf[4], vf[4];
#pragma unroll
            for (int mi = 0; mi < 4; ++mi)
                pf[mi] = *(const shortx8*)(Pw + (mi * 16 + l15) * 64 + coff);
#pragma unroll
            for (int nt = 0; nt < 4; ++nt)
                vf[nt] = *(const shortx8*)(Vs + (nt * 16 + l15) * 64 + coff);
#pragma unroll
            for (int mi = 0; mi < 4; ++mi)
#pragma unroll
                for (int nt = 0; nt < 4; ++nt)
                    O[mi][nt] = __builtin_amdgcn_mfma_f32_16x16x32_bf16(
                        pf[mi], vf[nt], O[mi][nt], 0, 0, 0);
        }
    }

    // reduce row sums across quads (lanes quad*16+l15 share q iff same l15)
#pragma unroll
    for (int qt = 0; qt < 4; ++qt) {
        lsum[qt] += __shfl_xor(lsum[qt], 16);
        lsum[qt] += __shfl_xor(lsum[qt], 32);
    }
    if (quad == 0) {
#pragma unroll
        for (int qt = 0; qt < 4; ++qt) Ls[w][qt * 16 + l15] = lsum[qt];
    }

    // epilogue: normalize, store att[n*SEQ+q][head*64+d] (bf16)
#pragma unroll
    for (int mi = 0; mi < 4; ++mi)
#pragma unroll
        for (int r = 0; r < 4; ++r) {
            const int   ql  = mi * 16 + quad * 4 + r;
            const float inv = 1.f / Ls[w][ql];
            const size_t row = (size_t)n * SEQ + q0 + ql;
#pragma unroll
            for (int nt = 0; nt < 4; ++nt)
                att[row * E_DIM + head * DHEAD + nt * 16 + l15] =
                    f2bf(O[mi][nt][r] * inv);
        }
}

// ------------------------------- launch ------------------------------------
extern "C" void kernel_launch(void* const* d_in, const int* in_sizes, int n_in,
                              void* d_out, int out_size, void* d_ws, size_t ws_size,
                              hipStream_t stream)
{
    const float* x  = (const float*)d_in[0];
    const float* W1 = (const float*)d_in[1];
    const float* b1 = (const float*)d_in[2];
    const float* W2 = (const float*)d_in[3];
    const float* b2 = (const float*)d_in[4];
    float* out = (float*)d_out;

    char* ws = (char*)d_ws;
    unsigned short* x_bf  = (unsigned short*)(ws);                    // 16 MB
    unsigned short* W1t   = (unsigned short*)(ws + (16u << 20));      //  6 MB
    unsigned short* W2t   = (unsigned short*)(ws + (22u << 20));      //  2 MB
    unsigned short* h_bf  = (unsigned short*)(ws + (24u << 20));      // 48 MB
    unsigned short* attb  = (unsigned short*)(ws + (72u << 20));      // 16 MB
    unsigned short* Vtw   = (unsigned short*)(ws + (88u << 20));      // 16 MB

    cvt_bf16<<<dim3((M_TOK * E_DIM) / (256 * 8)), 256, 0, stream>>>(x, x_bf);
    cvt_transpose<<<dim3(N1 / 32, E_DIM / 32), dim3(32, 8), 0, stream>>>(W1, W1t, E_DIM, N1);
    cvt_transpose<<<dim3(E_DIM / 32, E_DIM / 32), dim3(32, 8), 0, stream>>>(W2, W2t, E_DIM, E_DIM);

    // h = x@W1+b1 (bf16; Q cols pre-scaled log2(e)/8; V cols also -> Vt transposed)
    gemm_bf16<true, true><<<dim3(N1 / 128, M_TOK / 128), 256, 0, stream>>>(
        (const short*)x_bf, (const short*)W1t, b1, h_bf, Vtw, M_TOK, N1, E_DIM);

    attn_mfma<<<dim3(NB * NHEAD, SEQ / 128), 128, 0, stream>>>(
        (const short*)h_bf, (const short*)Vtw, attb);

    gemm_bf16<false, false><<<dim3(E_DIM / 128, M_TOK / 128), 256, 0, stream>>>(
        (const short*)attb, (const short*)W2t, b2, out, nullptr, M_TOK, E_DIM, E_DIM);
}

// Round 7
// 297.449 us; speedup vs baseline: 1.2485x; 1.2485x over previous
//
#include <hip/hip_runtime.h>
#include <math.h>
#include <stdint.h>
#include <stddef.h>

// ---------------------------------------------------------------------------
// SelfAttention forward, fp32 I/O, bf16 MFMA internally.
// Round 7: attention = cooperative wave-pairs. Block 256 thr / 4 waves /
// 2 pairs; each pair owns 64 q rows and a SHARED P buffer. Within a pair,
// wave e does S^T for kv-half e (writes its half of P), then PV over full P
// for d-half e (O split by d -> no O combine; only lsum exchanged via LDS).
// 2x waves/CU vs round 5 (16 vs 8): grid 1024 x 4 waves, 33.8 KB LDS.
// ---------------------------------------------------------------------------

#define SEQ    2048
#define NB     4
#define E_DIM  1024
#define N1     3072
#define M_TOK  8192
#define NHEAD  16
#define DHEAD  64

typedef __attribute__((ext_vector_type(4))) float    floatx4;
typedef __attribute__((ext_vector_type(8))) short    shortx8;
typedef __attribute__((ext_vector_type(4))) unsigned short ushortx4;

#if __has_builtin(__builtin_amdgcn_exp2f)
#define EXP2(x) __builtin_amdgcn_exp2f(x)
#else
#define EXP2(x) __expf((x) * 0.6931471805599453f)
#endif

__device__ __forceinline__ unsigned short f2bf(float f) {
    union { float f; unsigned u; } v; v.f = f;
    unsigned r = (v.u + 0x7FFFu + ((v.u >> 16) & 1u)) >> 16;  // RNE
    return (unsigned short)r;
}
__device__ __forceinline__ unsigned fbits(float f) {
    union { float f; unsigned u; } v; v.f = f; return v.u;
}
__device__ __forceinline__ float bitsf(unsigned u) {
    union { unsigned u; float f; } v; v.u = u; return v.f;
}

__device__ __forceinline__ void gl_lds16(const void* g, void* l) {
    __builtin_amdgcn_global_load_lds(
        (const __attribute__((address_space(1))) unsigned int*)g,
        (__attribute__((address_space(3))) unsigned int*)l, 16, 0, 0);
}

// --------------------------- fp32 -> bf16 convert ---------------------------
__global__ __launch_bounds__(256) void cvt_bf16(
    const float* __restrict__ in, unsigned short* __restrict__ out)
{
    const size_t i = ((size_t)blockIdx.x * 256 + threadIdx.x) * 8;
    float4 a = *(const float4*)(in + i);
    float4 b = *(const float4*)(in + i + 4);
    ushortx4 o0 = { f2bf(a.x), f2bf(a.y), f2bf(a.z), f2bf(a.w) };
    ushortx4 o1 = { f2bf(b.x), f2bf(b.y), f2bf(b.z), f2bf(b.w) };
    *(ushortx4*)(out + i)     = o0;
    *(ushortx4*)(out + i + 4) = o1;
}

// -------------------- fp32 [K][N] -> bf16 transposed [N][K] -----------------
__global__ __launch_bounds__(256) void cvt_transpose(
    const float* __restrict__ W, unsigned short* __restrict__ Wt, int K, int N)
{
    __shared__ unsigned short tile[32][33];
    const int tx = threadIdx.x, ty = threadIdx.y;   // (32, 8)
    const int n0 = blockIdx.x * 32, k0 = blockIdx.y * 32;
#pragma unroll
    for (int r = 0; r < 4; ++r) {
        const int k = ty + r * 8;
        tile[tx][k] = f2bf(W[(size_t)(k0 + k) * N + n0 + tx]);
    }
    __syncthreads();
#pragma unroll
    for (int r = 0; r < 4; ++r) {
        const int n = ty + r * 8;
        Wt[(size_t)(n0 + n) * K + k0 + tx] = tile[n][tx];
    }
}

// --------------------------- bf16 MFMA GEMM --------------------------------
// C[M,N] = A[M,K](bf16) @ Bt[N,K](bf16, pre-transposed) + bias[N](f32).
// FUSE (gemm1 only): Q columns (col%192 < 64) pre-scaled by log2(e)/8 before
// bf16 store (softmax becomes plain exp2); V columns (col%192 >= 128) also
// written transposed into Vt[bh][d][s] (4 consecutive rows per lane -> packed).
template <bool OUT_BF16, bool FUSE>
__global__ __launch_bounds__(256) void gemm_bf16(
    const short* __restrict__ A, const short* __restrict__ Bt,
    const float* __restrict__ bias, void* __restrict__ Cout,
    unsigned short* __restrict__ Vt,
    int M, int N, int K)
{
    __shared__ short As[128 * 32];
    __shared__ short Bs[128 * 32];

    const int t    = threadIdx.x;
    const int lane = t & 63, w = t >> 6;
    const int quad = lane >> 4, l15 = lane & 15;
    const int bm = blockIdx.y * 128, bn = blockIdx.x * 128;
    const int m0w = (w >> 1) * 64, n0w = (w & 1) * 64;

    const int lrow = lane >> 2;        // 0..15
    const int lcol = (lane & 3) * 8;   // 0,8,16,24
    const short* Ag0 = A  + (size_t)(bm + (2 * w + 0) * 16 + lrow) * K + lcol;
    const short* Ag1 = A  + (size_t)(bm + (2 * w + 1) * 16 + lrow) * K + lcol;
    const short* Bg0 = Bt + (size_t)(bn + (2 * w + 0) * 16 + lrow) * K + lcol;
    const short* Bg1 = Bt + (size_t)(bn + (2 * w + 1) * 16 + lrow) * K + lcol;
    short* Al0 = As + (2 * w + 0) * 512;
    short* Al1 = As + (2 * w + 1) * 512;
    short* Bl0 = Bs + (2 * w + 0) * 512;
    short* Bl1 = Bs + (2 * w + 1) * 512;

    floatx4 acc[4][4];
#pragma unroll
    for (int i = 0; i < 4; ++i)
#pragma unroll
        for (int j = 0; j < 4; ++j) acc[i][j] = (floatx4)0.f;

    for (int k0 = 0; k0 < K; k0 += 32) {
        __syncthreads();
        gl_lds16(Ag0, Al0); gl_lds16(Ag1, Al1);
        gl_lds16(Bg0, Bl0); gl_lds16(Bg1, Bl1);
        Ag0 += 32; Ag1 += 32; Bg0 += 32; Bg1 += 32;
        __syncthreads();

        shortx8 af[4], bf[4];
#pragma unroll
        for (int mi = 0; mi < 4; ++mi)
            af[mi] = *(const shortx8*)(As + (m0w + mi * 16 + l15) * 32 + quad * 8);
#pragma unroll
        for (int ni = 0; ni < 4; ++ni)
            bf[ni] = *(const shortx8*)(Bs + (n0w + ni * 16 + l15) * 32 + quad * 8);
#pragma unroll
        for (int mi = 0; mi < 4; ++mi)
#pragma unroll
            for (int ni = 0; ni < 4; ++ni)
                acc[mi][ni] = __builtin_amdgcn_mfma_f32_16x16x32_bf16(
                    af[mi], bf[ni], acc[mi][ni], 0, 0, 0);
    }

    float bv[4];
#pragma unroll
    for (int ni = 0; ni < 4; ++ni) bv[ni] = bias[bn + n0w + ni * 16 + l15];

#pragma unroll
    for (int ni = 0; ni < 4; ++ni) {
        const int col   = bn + n0w + ni * 16 + l15;
        const int cm    = col % 192;      // wave-uniform block (no divergence)
        const int vhead = col / 192;
#pragma unroll
        for (int mi = 0; mi < 4; ++mi) {
            const int row0 = bm + m0w + mi * 16 + quad * 4;
            float v[4];
#pragma unroll
            for (int r = 0; r < 4; ++r) v[r] = acc[mi][ni][r] + bv[ni];
            if (OUT_BF16) {
                if (FUSE && cm < DHEAD) {
#pragma unroll
                    for (int r = 0; r < 4; ++r) v[r] *= 0.18033688011112042f;  // log2(e)/8
                }
                unsigned short* H = (unsigned short*)Cout;
#pragma unroll
                for (int r = 0; r < 4; ++r)
                    H[(size_t)(row0 + r) * N + col] = f2bf(v[r]);
                if (FUSE && cm >= 2 * DHEAD) {
                    const int nb = row0 >> 11;       // batch
                    const int s  = row0 & 2047;
                    const int d  = cm - 2 * DHEAD;
                    ushortx4 pk = { f2bf(v[0]), f2bf(v[1]), f2bf(v[2]), f2bf(v[3]) };
                    *(ushortx4*)(Vt + ((size_t)(nb * NHEAD + vhead) * DHEAD + d) * SEQ + s) = pk;
                }
            } else {
                float* C = (float*)Cout;
#pragma unroll
                for (int r = 0; r < 4; ++r)
                    C[(size_t)(row0 + r) * N + col] = v[r];
            }
        }
    }
}

// ------------------------- MFMA flash attention v7 --------------------------
// 256 thr = 4 waves = 2 pairs. Pair p owns q rows q0..q0+63 and P[p] (shared).
// Wave e of pair: S^T for kv slabs {2e,2e+1} -> its half of P; barrier;
// PV over FULL P but only d-half e (O split by d, no combine). lsum exchanged
// via tiny LDS. Grid (64 bh, 16 q-chunks) = 1024 blocks -> 16 waves/CU.
__global__ __launch_bounds__(256, 4) void attn_mfma(
    const short* __restrict__ h, const short* __restrict__ Vt,
    unsigned short* __restrict__ att)
{
    __shared__ short Ks[64 * 64];       // [kv][d], XOR8-swizzled
    __shared__ short Vs[64 * 64];       // [d][kv], XOR8-swizzled
    __shared__ short Pl[2][64 * 64];    // per-PAIR P [q][kv], XOR8-swizzled
    __shared__ float Ls2[2][2][64];     // [pair][kvhalf][q] row sums

    const int t    = threadIdx.x;
    const int lane = t & 63, w = t >> 6;
    const int p    = w >> 1, e = w & 1;
    const int quad = lane >> 4, l15 = lane & 15;
    const int r7   = l15 & 7;
    const int bh = blockIdx.x, n = bh >> 4, head = bh & 15;
    const int q0 = blockIdx.y * 128 + p * 64;

    const short* hQ  = h + (size_t)n * SEQ * N1 + head * (3 * DHEAD);
    const short* hK  = hQ + DHEAD;
    const short* Vtb = Vt + (size_t)bh * DHEAD * SEQ;

    // staging: thread t owns row t>>2, chunks (t&3)*2, +1 (2 int4 K, 2 int4 V)
    const int srow = t >> 2;
    const int sc0  = (t & 3) * 2;
    const int sk   = srow & 7;
    const short* gK = hK  + (size_t)srow * N1  + sc0 * 8;
    const short* gV = Vtb + (size_t)srow * SEQ + sc0 * 8;
    short* lK0 = Ks + srow * 64 + ((sc0    ) ^ sk) * 8;
    short* lK1 = Ks + srow * 64 + ((sc0 + 1) ^ sk) * 8;
    short* lV0 = Vs + srow * 64 + ((sc0    ) ^ sk) * 8;
    short* lV1 = Vs + srow * 64 + ((sc0 + 1) ^ sk) * 8;

    // Q fragments (both waves of a pair load the same rows; L1/L2 absorbs)
    shortx8 qf[4][2];
#pragma unroll
    for (int qt = 0; qt < 4; ++qt)
#pragma unroll
        for (int kt = 0; kt < 2; ++kt)
            qf[qt][kt] = *(const shortx8*)(hQ + (size_t)(q0 + qt * 16 + l15) * N1
                                           + kt * 32 + quad * 8);

    floatx4 O[4][2];                    // d-half e only: d=(2e+ntl)*16+l15
    float lsum[4];
#pragma unroll
    for (int mi = 0; mi < 4; ++mi) {
        lsum[mi] = 0.f;
#pragma unroll
        for (int nt = 0; nt < 2; ++nt) O[mi][nt] = (floatx4)0.f;
    }

    // prefetch tile 0
    int4 ka = *(const int4*)gK, kb = *(const int4*)(gK + 8);
    int4 va = *(const int4*)gV, vb = *(const int4*)(gV + 8);

    short* Pp = Pl[p];

    for (int kv0 = 0; kv0 < SEQ; kv0 += 64) {
        __syncthreads();                       // prev PV reads of P/Vs done
        *(int4*)lK0 = ka;
        *(int4*)lK1 = kb;
        *(int4*)lV0 = va;
        *(int4*)lV1 = vb;
        __syncthreads();                       // K/V tile ready
        if (kv0 + 64 < SEQ) {
            const short* gKn = gK + (size_t)(kv0 + 64) * N1;
            const short* gVn = gV + (kv0 + 64);
            ka = *(const int4*)gKn; kb = *(const int4*)(gKn + 8);
            va = *(const int4*)gVn; vb = *(const int4*)(gVn + 8);
        }

        // S^T for this wave's kv-half: slabs 2e, 2e+1 (16 kv each)
#pragma unroll
        for (int ii = 0; ii < 2; ++ii) {
            const int si = 2 * e + ii;
            const short* krow = Ks + (si * 16 + l15) * 64;
            shortx8 kf0 = *(const shortx8*)(krow + ((quad ^ r7) * 8));
            shortx8 kf1 = *(const shortx8*)(krow + (((quad ^ 4) ^ r7) * 8));
            floatx4 s[4];
#pragma unroll
            for (int qt = 0; qt < 4; ++qt) {
                s[qt] = __builtin_amdgcn_mfma_f32_16x16x32_bf16(
                    kf0, qf[qt][0], (floatx4)0.f, 0, 0, 0);
                s[qt] = __builtin_amdgcn_mfma_f32_16x16x32_bf16(
                    kf1, qf[qt][1], s[qt], 0, 0, 0);
            }
#pragma unroll
            for (int qt = 0; qt < 4; ++qt) {
                const float p0 = EXP2(s[qt][0]);
                const float p1 = EXP2(s[qt][1]);
                const float p2 = EXP2(s[qt][2]);
                const float p3 = EXP2(s[qt][3]);
                const unsigned d01 = __builtin_amdgcn_perm(fbits(p1), fbits(p0), 0x07060302u);
                const unsigned d23 = __builtin_amdgcn_perm(fbits(p3), fbits(p2), 0x07060302u);
                lsum[qt] += bitsf(d01 << 16) + bitsf(d01 & 0xFFFF0000u)
                          + bitsf(d23 << 16) + bitsf(d23 & 0xFFFF0000u);
                uint2 pk = { d01, d23 };
                *(uint2*)(Pp + (qt * 16 + l15) * 64
                          + ((si * 2 + (quad >> 1)) ^ r7) * 8 + (quad & 1) * 4) = pk;
            }
        }
        __syncthreads();                       // pair's P complete

        // O += P @ V   (full P, d-half e)
#pragma unroll
        for (int kt2 = 0; kt2 < 2; ++kt2) {
            const int coff = ((kt2 * 4 + quad) ^ r7) * 8;
            shortx8 pf[4], vf[2];
#pragma unroll
            for (int mi = 0; mi < 4; ++mi)
                pf[mi] = *(const shortx8*)(Pp + (mi * 16 + l15) * 64 + coff);
#pragma unroll
            for (int nt = 0; nt < 2; ++nt)
                vf[nt] = *(const shortx8*)(Vs + ((2 * e + nt) * 16 + l15) * 64 + coff);
#pragma unroll
            for (int mi = 0; mi < 4; ++mi)
#pragma unroll
                for (int nt = 0; nt < 2; ++nt)
                    O[mi][nt] = __builtin_amdgcn_mfma_f32_16x16x32_bf16(
                        pf[mi], vf[nt], O[mi][nt], 0, 0, 0);
        }
    }

    // row sums: reduce across quads, then exchange between the pair's waves
#pragma unroll
    for (int qt = 0; qt < 4; ++qt) {
        lsum[qt] += __shfl_xor(lsum[qt], 16);
        lsum[qt] += __shfl_xor(lsum[qt], 32);
    }
    if (quad == 0) {
#pragma unroll
        for (int qt = 0; qt < 4; ++qt) Ls2[p][e][qt * 16 + l15] = lsum[qt];
    }
    __syncthreads();

    // epilogue: normalize by (half0+half1) sums, store att bf16
#pragma unroll
    for (int mi = 0; mi < 4; ++mi)
#pragma unroll
        for (int r = 0; r < 4; ++r) {
            const int   ql  = mi * 16 + quad * 4 + r;
            const float inv = 1.f / (Ls2[p][0][ql] + Ls2[p][1][ql]);
            const size_t row = (size_t)n * SEQ + q0 + ql;
#pragma unroll
            for (int nt = 0; nt < 2; ++nt)
                att[row * E_DIM + head * DHEAD + (2 * e + nt) * 16 + l15] =
                    f2bf(O[mi][nt][r] * inv);
        }
}

// ------------------------------- launch ------------------------------------
extern "C" void kernel_launch(void* const* d_in, const int* in_sizes, int n_in,
                              void* d_out, int out_size, void* d_ws, size_t ws_size,
                              hipStream_t stream)
{
    const float* x  = (const float*)d_in[0];
    const float* W1 = (const float*)d_in[1];
    const float* b1 = (const float*)d_in[2];
    const float* W2 = (const float*)d_in[3];
    const float* b2 = (const float*)d_in[4];
    float* out = (float*)d_out;

    char* ws = (char*)d_ws;
    unsigned short* x_bf  = (unsigned short*)(ws);                    // 16 MB
    unsigned short* W1t   = (unsigned short*)(ws + (16u << 20));      //  6 MB
    unsigned short* W2t   = (unsigned short*)(ws + (22u << 20));      //  2 MB
    unsigned short* h_bf  = (unsigned short*)(ws + (24u << 20));      // 48 MB
    unsigned short* attb  = (unsigned short*)(ws + (72u << 20));      // 16 MB
    unsigned short* Vtw   = (unsigned short*)(ws + (88u << 20));      // 16 MB

    cvt_bf16<<<dim3((M_TOK * E_DIM) / (256 * 8)), 256, 0, stream>>>(x, x_bf);
    cvt_transpose<<<dim3(N1 / 32, E_DIM / 32), dim3(32, 8), 0, stream>>>(W1, W1t, E_DIM, N1);
    cvt_transpose<<<dim3(E_DIM / 32, E_DIM / 32), dim3(32, 8), 0, stream>>>(W2, W2t, E_DIM, E_DIM);

    // h = x@W1+b1 (bf16; Q cols pre-scaled log2(e)/8; V cols also -> Vt transposed)
    gemm_bf16<true, true><<<dim3(N1 / 128, M_TOK / 128), 256, 0, stream>>>(
        (const short*)x_bf, (const short*)W1t, b1, h_bf, Vtw, M_TOK, N1, E_DIM);

    attn_mfma<<<dim3(NB * NHEAD, SEQ / 128), 256, 0, stream>>>(
        (const short*)h_bf, (const short*)Vtw, attb);

    gemm_bf16<false, false><<<dim3(E_DIM / 128, M_TOK / 128), 256, 0, stream>>>(
        (const short*)attb, (const short*)W2t, b2, out, nullptr, M_TOK, E_DIM, E_DIM);
}